// Round 3
// baseline (219.057 us; speedup 1.0000x reference)
//
#include <hip/hip_runtime.h>
#include <hip/hip_bf16.h>
#include <cstdint>
#include <cstddef>

#define NB   32
#define CIN  128
#define HWP  3136          // 56*56
#define KOC  256
#define NRS  9
#define PSTR 58            // padded row stride (w: -1..56)
#define PROW 3364          // 58*58 padded rows per (n,ck)
#define WIN  256           // halo window rows staged per ck
#define WINB (WIN * 64)    // bytes per LDS buffer = 16384

typedef __attribute__((ext_vector_type(8))) short  short8;
typedef __attribute__((ext_vector_type(4))) short  short4v;
typedef __attribute__((ext_vector_type(4))) float  float4v;

__device__ __forceinline__ unsigned short f2bf(float f) {
    union { float f; unsigned int u; } v; v.f = f;
    unsigned int u = v.u;
    u = u + 0x7fffu + ((u >> 16) & 1u);   // RNE
    return (unsigned short)(u >> 16);
}

// ---------------------------------------------------------------------------
// Fused prep kernel, three independent jobs (disjoint outputs, no ordering):
//   blocks [0, 1152):      W (OIHW fp32) -> wt2 MFMA-fragment order
//   blocks [1152, 2816):   x NCHW fp32 -> xt[n][ck][p'][32c] bf16 halo layout
//   blocks [2816, 2930):   zero the 228 guard rows per (n,ck) slab
// ---------------------------------------------------------------------------
__global__ __launch_bounds__(256) void prep_kernel(const float* __restrict__ W,
                                                   unsigned short* __restrict__ wt2,
                                                   const float* __restrict__ x,
                                                   unsigned short* __restrict__ xt) {
    __shared__ unsigned short lds[32 * 260];
    int blk = blockIdx.x;
    int t   = threadIdx.x;

    if (blk < 1152) {
        // ---- wt2 part ----
        int idx = blk * 256 + t;
        int e    = idx & 7;
        int lr   = (idx >> 3) & 15;
        int quad = (idx >> 7) & 3;
        int i    = (idx >> 9) & 3;
        int wm   = (idx >> 11) & 1;
        int ot   = (idx >> 12) & 1;
        int ck   = (idx >> 13) & 3;
        int rs   = idx >> 15;
        int oc = ot * 128 + wm * 64 + i * 16 + lr;
        int c  = ck * 32 + quad * 8 + e;
        wt2[idx] = f2bf(W[((size_t)oc * CIN + c) * NRS + rs]);
        return;
    }

    if (blk >= 2816) {
        // ---- guard-zero part: 128 slabs x 228 guard rows, 64 B each ----
        int g = (blk - 2816) * 256 + t;            // 0 .. 29183 (exact)
        int slab = g / 228;
        int gi   = g - slab * 228;
        int row;
        if (gi < 59)       row = gi;                               // top halo
        else if (gi < 169) { int k = gi - 59;                      // seam gaps
                             row = 115 + 58 * (k >> 1) + (k & 1); }
        else               row = 3305 + (gi - 169);                // bottom halo
        unsigned short* gr = xt + (size_t)slab * (PROW * 32) + (size_t)row * 32;
        short8 z = (short8)0;
        *(short8*)(gr +  0) = z;
        *(short8*)(gr +  8) = z;
        *(short8*)(gr + 16) = z;
        *(short8*)(gr + 24) = z;
        return;
    }

    // ---- xpose part (interior rows) ----
    int b    = blk - 1152;
    int tile = b % 13;
    int ck   = (b / 13) & 3;
    int n    = b / 52;
    int hw0  = tile * 256;
    int wv   = t >> 6;
    int lane = t & 63;

    const float* src = x + ((size_t)(n * CIN + ck * 32)) * HWP;
    #pragma unroll
    for (int pass = 0; pass < 8; ++pass) {
        int c  = pass * 4 + wv;
        int hw = hw0 + lane * 4;
        if (hw < HWP) {
            float4v v = *(const float4v*)(src + (size_t)c * HWP + hw);
            short4v s4;
            #pragma unroll
            for (int k = 0; k < 4; ++k) s4[k] = (short)f2bf(v[k]);
            *(short4v*)(&lds[c * 260 + lane * 4]) = s4;
        }
    }
    __syncthreads();

    int sub = t & 3;
    int hwl = t >> 2;
    unsigned short* dst = xt + ((size_t)(n * 4 + ck)) * PROW * 32;
    #pragma unroll
    for (int pass = 0; pass < 4; ++pass) {
        int hl = pass * 64 + hwl;
        int hw = hw0 + hl;
        if (hw < HWP) {
            short8 v;
            #pragma unroll
            for (int j = 0; j < 8; ++j)
                v[j] = (short)lds[(sub * 8 + j) * 260 + hl];
            int pr = hw + 59 + 2 * (hw / 56);
            *(short8*)(dst + (size_t)pr * 32 + sub * 8) = v;
        }
    }
}

// ---------------------------------------------------------------------------
// Stage one 256-row halo window (16 KB) into LDS via async global_load_lds.
// XOR swizzle: LDS slot (r,q) holds global 16B-chunk (r, q ^ ((r>>1)&3)).
// 8 waves x 2 iterations cover all 1024 slots.
// ---------------------------------------------------------------------------
__device__ __forceinline__ void stage_window(const unsigned short* gwin,
                                             unsigned short* lwin,
                                             int wv, int lane) {
    #pragma unroll
    for (int it = 0; it < 2; ++it) {
        int blk = it * 8 + wv;             // wave-chunk 0..15 (wave-uniform)
        int s   = blk * 64 + lane;         // slot 0..1023
        int r   = s >> 2;
        int q   = s & 3;
        int qs  = q ^ ((r >> 1) & 3);
        const char* g = (const char*)gwin + r * 64 + qs * 16;
        char*       l = (char*)lwin + blk * 1024;   // uniform base; lane*16 implicit
        __builtin_amdgcn_global_load_lds(
            (const __attribute__((address_space(1))) void*)g,
            (__attribute__((address_space(3))) void*)l, 16, 0, 0);
    }
}

__device__ __forceinline__ short8 ldb(const char* lb, int r, int quad) {
    int q = quad ^ ((r >> 1) & 3);
    return *(const short8*)(lb + r * 64 + q * 16);
}

// ---------------------------------------------------------------------------
// Implicit GEMM, 128 oc x 128 px per block, 8 waves (2 oc-half x 4 px-quarter),
// wave tile 64 oc x 32 px via 4x2 mfma_f32_16x16x32_bf16.
//
// Occupancy/register plan: acc 32 AGPR + afc/afn 32 + B 8 + addr ~15 ~= 90
// unified regs << 128 cap from __launch_bounds__(512, 4) (= 4 waves/SIMD,
// 2 blocks/CU, LDS 2x32KB = 64KB). Previous 4-wave/acc-64 version pinned the
// arch file at exactly 64 (128 cap - 64 AGPR) and spilled ~70 MB/dispatch to
// scratch (WRITE_SIZE 169-182 MB vs 100 MB output).
//
// vmcnt queue discipline: next-ck staging (global_load_lds) is issued at the
// END of the ck body, AFTER all per-step A prefetch loads. vmcnt completes
// in issue order, so staging issued up front would make every per-step
// s_waitcnt for the A ping-pong transitively wait on the 16 KB DMA
// (~400-800 cyc) -- the A double-buffer was dead weight. Stage-late keeps
// per-step waits at vmcnt(4); the one-per-ck __syncthreads drain eats the
// residual staging latency, covered by the other resident block.
// ---------------------------------------------------------------------------
__global__ __launch_bounds__(512, 4) void gemm_kernel(const unsigned short* __restrict__ xt,
                                                      const unsigned short* __restrict__ wt2,
                                                      const float* __restrict__ bias,
                                                      float* __restrict__ out) {
    __shared__ unsigned short b_lds[2 * WIN * 32];   // 32 KB, double-buffered

    int bx  = blockIdx.x;                 // 25 pt x 32 n x 2 ot = 1600
    int ot  = bx & 1;
    int n   = (bx >> 1) & 31;
    int pt  = bx >> 6;
    int oc0 = ot * 128;
    int p0  = pt * 128;

    int t    = threadIdx.x;
    int wv   = t >> 6;                    // 0..7
    int lane = t & 63;
    int lr   = lane & 15;
    int quad = lane >> 4;
    int wm   = wv >> 2;                   // oc half (64 oc)
    int wn   = wv & 3;                    // px quarter (32 px)

    int prbase = p0 + 2 * (p0 / 56);      // = pr(p0) - 59, >= 0

    // per-j window row of the center tap (shift 0); clamped for tail tile
    int rb[2];
    #pragma unroll
    for (int j = 0; j < 2; ++j) {
        int hw  = p0 + wn * 32 + j * 16 + lr;
        int hwc = hw < HWP ? hw : (HWP - 1);
        rb[j] = hwc + 59 + 2 * (hwc / 56) - prbase;   // in [59, 252)
    }

    const unsigned short* xb = xt + (size_t)n * 4 * PROW * 32;

    float4v acc[4][2];
    #pragma unroll
    for (int i = 0; i < 4; ++i)
        #pragma unroll
        for (int j = 0; j < 2; ++j)
            acc[i][j] = (float4v){0.f, 0.f, 0.f, 0.f};

    // A running pointer: (rs,ck) slab = ((rs*4+ck)*2+ot)*4096 + wm*2048 + lane*8
    const unsigned short* ap = wt2 + (ot * 4096 + wm * 2048 + lane * 8);
    short8 afc[4];
    #pragma unroll
    for (int i = 0; i < 4; ++i) afc[i] = *(const short8*)(ap + i * 512);

    // prologue: stage ck=0 window into buffer 0
    stage_window(xb + (size_t)prbase * 32, b_lds, wv, lane);

    const int SH[9] = {-59, -58, -57, -1, 0, 1, 57, 58, 59};

    for (int ck = 0; ck < 4; ++ck) {
        __syncthreads();    // drains staging of buf[ck&1] (+ prior A loads)
        const char* lb = (const char*)b_lds + (ck & 1) * WINB;

        #pragma unroll
        for (int rs = 0; rs < 9; ++rs) {
            // prefetch next step's A (wraps to next ck; last wrap reads valid junk)
            ap += (rs == 8) ? -253952 : 32768;
            short8 afn[4];
            #pragma unroll
            for (int i = 0; i < 4; ++i) afn[i] = *(const short8*)(ap + i * 512);
            // B two-deep rotation within the step
            short8 bcur = ldb(lb, rb[0] + SH[rs], quad);
            #pragma unroll
            for (int j = 0; j < 2; ++j) {
                short8 bnext;
                if (j < 1) bnext = ldb(lb, rb[j + 1] + SH[rs], quad);
                #pragma unroll
                for (int i = 0; i < 4; ++i)
                    acc[i][j] = __builtin_amdgcn_mfma_f32_16x16x32_bf16(
                        afc[i], bcur, acc[i][j], 0, 0, 0);
                if (j < 1) bcur = bnext;
            }
            #pragma unroll
            for (int i = 0; i < 4; ++i) afc[i] = afn[i];
        }

        // stage-late: issue next window AFTER this ck's A loads so the
        // per-step vmcnt waits never cover the staging DMA
        if (ck < 3)
            stage_window(xb + (size_t)(ck + 1) * (PROW * 32) + (size_t)prbase * 32,
                         (unsigned short*)(b_lds) + ((ck + 1) & 1) * (WIN * 32),
                         wv, lane);
    }

    // epilogue: D row = oc (quad*4+reg), col = pixel (lane&15)
    float* orow = out + (size_t)n * KOC * HWP;
    #pragma unroll
    for (int i = 0; i < 4; ++i) {
        #pragma unroll
        for (int r = 0; r < 4; ++r) {
            int oc = oc0 + wm * 64 + i * 16 + quad * 4 + r;
            float bi = bias[oc];
            #pragma unroll
            for (int j = 0; j < 2; ++j) {
                int hw = p0 + wn * 32 + j * 16 + lr;
                if (hw < HWP)
                    orow[(size_t)oc * HWP + hw] = acc[i][j][r] + bi;
            }
        }
    }
}

// ---------------------------------------------------------------------------
// Safety fallback if ws is too small: naive direct conv (exact fp32).
// ---------------------------------------------------------------------------
__global__ void naive_kernel(const float* __restrict__ x, const float* __restrict__ W,
                             const float* __restrict__ b, float* __restrict__ out) {
    size_t idx = (size_t)blockIdx.x * 256 + threadIdx.x;
    if (idx >= (size_t)NB * KOC * HWP) return;
    int w0 = (int)(idx % 56);
    int h0 = (int)((idx / 56) % 56);
    int k  = (int)((idx / HWP) % KOC);
    int n  = (int)(idx / ((size_t)HWP * KOC));
    float acc = b[k];
    for (int c = 0; c < CIN; ++c) {
        const float* xr = x + ((size_t)n * CIN + c) * HWP;
        const float* wr = W + ((size_t)k * CIN + c) * NRS;
        for (int r = 0; r < 3; ++r) {
            int h = h0 + r - 1;
            if ((unsigned)h >= 56u) continue;
            for (int s = 0; s < 3; ++s) {
                int w = w0 + s - 1;
                if ((unsigned)w >= 56u) continue;
                acc += xr[h * 56 + w] * wr[r * 3 + s];
            }
        }
    }
    out[idx] = acc;
}

extern "C" void kernel_launch(void* const* d_in, const int* in_sizes, int n_in,
                              void* d_out, int out_size, void* d_ws, size_t ws_size,
                              hipStream_t stream) {
    const float* x  = (const float*)d_in[0];
    const float* W  = (const float*)d_in[1];
    const float* b  = (const float*)d_in[2];
    float* out = (float*)d_out;

    const size_t wt_elems = (size_t)NRS * 4 * 2 * 2 * 4 * 4 * 16 * 8;   // 294912
    const size_t xt_elems = (size_t)NB * 4 * PROW * 32 + WIN * 32;      // + staging guard
    const size_t need = (wt_elems + xt_elems) * sizeof(unsigned short); // ~28.2 MB

    if (ws_size < need) {
        size_t total = (size_t)NB * KOC * HWP;
        naive_kernel<<<(unsigned)((total + 255) / 256), 256, 0, stream>>>(x, W, b, out);
        return;
    }

    unsigned short* wt2 = (unsigned short*)d_ws;
    unsigned short* xt  = wt2 + wt_elems;        // 16B-aligned

    // prep zeroes only the 228 guard rows per slab (no full-buffer memset)
    prep_kernel<<<1152 + NB * 4 * 13 + 114, 256, 0, stream>>>(W, wt2, x, xt);
    gemm_kernel<<<1600, 512, 0, stream>>>(xt, wt2, b, out);
}